// Round 23
// baseline (159.465 us; speedup 1.0000x reference)
//
#include <hip/hip_runtime.h>

#define D 64
#define FPAD 65

__device__ __forceinline__ float relu_f(float v) { return v > 0.f ? v : 0.f; }

// f32 -> bf16 (round-to-nearest-even); inputs are finite post-relu values
__device__ __forceinline__ unsigned short f2bf(float f) {
    unsigned u = __builtin_bit_cast(unsigned, f);
    u = (u + 0x7FFFu + ((u >> 16) & 1u)) >> 16;
    return (unsigned short)u;
}
__device__ __forceinline__ float bf2f(unsigned short h) {
    return __builtin_bit_cast(float, (unsigned)h << 16);
}

// ---------------- fused prep: zero cnt | pair table | Q table ----------------
__global__ __launch_bounds__(256) void k_prep(int* __restrict__ cnt, int En,
        const float* __restrict__ fe, const float* __restrict__ W1,
        float* __restrict__ P, int nrel,
        const float* __restrict__ mW1, const float* __restrict__ mb1,
        float* __restrict__ Q, int nZ, int nP) {
    __shared__ float Wl[64 * 64];
    __shared__ float fT[64 * FPAD];
    const int tid = threadIdx.x;
    int b = blockIdx.x;

    if (b < nZ) {                       // ---- zero ----
        int i = (b * 256 + tid) * 4;
        if (i + 3 < En) {
            *reinterpret_cast<int4*>(cnt + i) = make_int4(0, 0, 0, 0);
        } else {
            for (int k = i; k < En; ++k) cnt[k] = 0;
        }
        return;
    }
    b -= nZ;
    if (b < nP) {                       // ---- pair table ----
        const int npair = nrel * nrel;
        const int p0 = b * 64;

        for (int i = tid; i < 1024; i += 256)
            reinterpret_cast<float4*>(Wl)[i] = reinterpret_cast<const float4*>(W1)[i];

        for (int i = tid; i < 1024; i += 256) {
            int r = i >> 4, q = i & 15;
            int p = p0 + r;
            float4 v = make_float4(0.f, 0.f, 0.f, 0.f);
            if (p < npair) {
                int pa = p / nrel, pb = p - pa * nrel;
                float4 va = reinterpret_cast<const float4*>(fe + (size_t)pa * D)[q];
                float4 vb = reinterpret_cast<const float4*>(fe + (size_t)pb * D)[q];
                v = make_float4(va.x * vb.x, va.y * vb.y, va.z * vb.z, va.w * vb.w);
            }
            fT[(q * 4 + 0) * FPAD + r] = v.x;
            fT[(q * 4 + 1) * FPAD + r] = v.y;
            fT[(q * 4 + 2) * FPAD + r] = v.z;
            fT[(q * 4 + 3) * FPAD + r] = v.w;
        }
        __syncthreads();

        const int j0 = (tid & 15) * 4;
        const int r0 = (tid >> 4) * 4;
        float acc[4][4];
        #pragma unroll
        for (int i = 0; i < 4; ++i)
            #pragma unroll
            for (int j = 0; j < 4; ++j) acc[i][j] = 0.f;

        #pragma unroll 8
        for (int k = 0; k < 64; ++k) {
            float4 f = *reinterpret_cast<const float4*>(&fT[k * FPAD + r0]);
            float4 w = *reinterpret_cast<const float4*>(&Wl[k * 64 + j0]);
            float fa[4] = {f.x, f.y, f.z, f.w};
            float wa[4] = {w.x, w.y, w.z, w.w};
            #pragma unroll
            for (int i = 0; i < 4; ++i)
                #pragma unroll
                for (int j = 0; j < 4; ++j) acc[i][j] += fa[i] * wa[j];
        }

        #pragma unroll
        for (int i = 0; i < 4; ++i) {
            int p = p0 + r0 + i;
            if (p < npair) {
                float4 o = make_float4(acc[i][0], acc[i][1], acc[i][2], acc[i][3]);
                *reinterpret_cast<float4*>(P + (size_t)p * D + j0) = o;
            }
        }
        return;
    }
    b -= nP;                            // ---- Q table (2 t's per block) ----
    int t = b * 2 + (tid >> 7);
    int j = tid & 127;
    float* fl = &fT[(tid >> 7) * 64];
    if (t < nrel && j < 64) fl[j] = fe[(size_t)t * D + j];
    __syncthreads();
    if (t < nrel) {
        float s = mb1[j];
        #pragma unroll 16
        for (int k = 0; k < 64; ++k)
            s += fl[k] * mW1[(size_t)(64 + k) * 128 + j];
        Q[(size_t)t * 128 + j] = s;
    }
}

// ---------------- CSR build ----------------

__global__ void k_hist(const int* __restrict__ ac, int* __restrict__ cnt, int T) {
    int t = blockIdx.x * blockDim.x + threadIdx.x;
    if (t < T) atomicAdd(&cnt[ac[t]], 1);
}

__global__ __launch_bounds__(256) void k_scanA(const int* __restrict__ cnt,
        int* __restrict__ localExcl, int* __restrict__ blockSums, int E) {
    __shared__ int ls[256];
    const int tid = threadIdx.x;
    int base = blockIdx.x * 1024 + tid * 4;
    int a0 = 0, a1 = 0, a2 = 0, a3 = 0;
    if (base + 3 < E) {
        int4 v = *reinterpret_cast<const int4*>(cnt + base);
        a0 = v.x; a1 = v.y; a2 = v.z; a3 = v.w;
    } else {
        if (base + 0 < E) a0 = cnt[base + 0];
        if (base + 1 < E) a1 = cnt[base + 1];
        if (base + 2 < E) a2 = cnt[base + 2];
        if (base + 3 < E) a3 = cnt[base + 3];
    }
    int tsum = a0 + a1 + a2 + a3;
    ls[tid] = tsum;
    __syncthreads();
    for (int off = 1; off < 256; off <<= 1) {
        int v = (tid >= off) ? ls[tid - off] : 0;
        __syncthreads();
        ls[tid] += v;
        __syncthreads();
    }
    int excl = ls[tid] - tsum;
    if (tid == 255) blockSums[blockIdx.x] = ls[255];
    if (base + 3 < E) {
        int4 o = make_int4(excl, excl + a0, excl + a0 + a1, excl + a0 + a1 + a2);
        *reinterpret_cast<int4*>(localExcl + base) = o;
    } else {
        int run = excl;
        if (base + 0 < E) { localExcl[base + 0] = run; run += a0; }
        if (base + 1 < E) { localExcl[base + 1] = run; run += a1; }
        if (base + 2 < E) { localExcl[base + 2] = run; run += a2; }
        if (base + 3 < E) { localExcl[base + 3] = run; }
    }
}

// scanC with integrated scan of blockSums (nblk <= 256)
__global__ __launch_bounds__(256) void k_scanC(const int* __restrict__ localExcl,
        const int* __restrict__ blockSums, const int* __restrict__ cnt,
        int2* __restrict__ seg, int* __restrict__ cursor, int E, int nblk) {
    __shared__ int ls[256];
    const int tid = threadIdx.x;
    int v = (tid < nblk) ? blockSums[tid] : 0;
    ls[tid] = v;
    __syncthreads();
    for (int off = 1; off < 256; off <<= 1) {
        int w = (tid >= off) ? ls[tid - off] : 0;
        __syncthreads();
        ls[tid] += w;
        __syncthreads();
    }
    int excl = ls[tid] - v;     // exclusive prefix of blockSums
    __syncthreads();
    ls[tid] = excl;
    __syncthreads();
    int i = blockIdx.x * blockDim.x + tid;
    if (i < E) {
        int s = localExcl[i] + ls[i >> 10];
        seg[i] = make_int2(s, cnt[i]);
        cursor[i] = s;
    }
}

// tri[pos] = (ab, bc); pid[pos] = et[ab]*nrel + et[bc]
__global__ void k_permute(const int* __restrict__ ab, const int* __restrict__ bc,
                          const int* __restrict__ ac, const int* __restrict__ et,
                          int* __restrict__ cursor, int2* __restrict__ tri,
                          int* __restrict__ pid, int T, int nrel) {
    int t = blockIdx.x * blockDim.x + threadIdx.x;
    if (t >= T) return;
    int a = ab[t], b = bc[t];
    int pos = atomicAdd(&cursor[ac[t]], 1);
    tri[pos] = make_int2(a, b);
    pid[pos] = et[a] * nrel + et[b];
}

// ---------------- layer-1: xb[e] = relu(sum_t P[pid_t] + b1), bf16 output ----
__global__ __launch_bounds__(256) void k_msg1b(const int2* __restrict__ seg,
        const int* __restrict__ pid, const float* __restrict__ P,
        const float* __restrict__ b1, unsigned short* __restrict__ xb,
        int E, int nquad) {
    const int tid = threadIdx.x;
    const int lane = tid & 63;
    const int sub = lane & 15;
    const int grp = lane >> 4;
    const float4* __restrict__ P4 = reinterpret_cast<const float4*>(P);
    const float4 bb = reinterpret_cast<const float4*>(b1)[sub];

    for (int quad = (blockIdx.x * blockDim.x + tid) >> 6; quad * 4 < E; quad += nquad) {
        const int e = quad * 4 + grp;
        int2 sc = make_int2(0, 0);
        if (e < E) sc = seg[e];
        const int s = sc.x, c = sc.y;
        float4 acc = make_float4(0.f, 0.f, 0.f, 0.f);
        int i = 0;
        for (; i + 3 < c; i += 4) {
            int q0 = pid[s + i + 0];
            int q1 = pid[s + i + 1];
            int q2 = pid[s + i + 2];
            int q3 = pid[s + i + 3];
            float4 v0 = P4[(size_t)q0 * 16 + sub];
            float4 v1 = P4[(size_t)q1 * 16 + sub];
            float4 v2 = P4[(size_t)q2 * 16 + sub];
            float4 v3 = P4[(size_t)q3 * 16 + sub];
            acc.x += v0.x + v1.x + v2.x + v3.x;
            acc.y += v0.y + v1.y + v2.y + v3.y;
            acc.z += v0.z + v1.z + v2.z + v3.z;
            acc.w += v0.w + v1.w + v2.w + v3.w;
        }
        for (; i < c; ++i) {
            float4 v = P4[(size_t)pid[s + i] * 16 + sub];
            acc.x += v.x; acc.y += v.y; acc.z += v.z; acc.w += v.w;
        }
        if (e < E) {
            ushort4 o;
            o.x = f2bf(relu_f(acc.x + bb.x));
            o.y = f2bf(relu_f(acc.y + bb.y));
            o.z = f2bf(relu_f(acc.z + bb.z));
            o.w = f2bf(relu_f(acc.w + bb.w));
            reinterpret_cast<ushort4*>(xb)[(size_t)e * 16 + sub] = o;
        }
    }
}

// ---------------- fused layer-2: gather(bf16) + linear + final MLP ----------------
// Round-22 config (64 edges / 256 thr, Wl 8KB k-half staging, fT 16.6KB).
// Gather reads bf16 xb rows (128 B/row): traffic halved vs f32.
__global__ __launch_bounds__(256) void k_msgmlp(const int2* __restrict__ seg,
        const int2* __restrict__ tri, const unsigned short* __restrict__ xin,
        const int* __restrict__ et, const float* __restrict__ Q,
        const float* __restrict__ W2, const float* __restrict__ b2,
        const float* __restrict__ mW1, const float* __restrict__ mW2,
        const float* __restrict__ mb2, float* __restrict__ out, int E) {
    __shared__ float Wl[32 * 64];       // 8 KB: one k-half of a 64-col panel
    __shared__ float fT[64 * FPAD];     // 16.6 KB (agg^T, then xa^T)
    const int tid = threadIdx.x;
    const int row0 = blockIdx.x * 64;
    const int lane = tid & 63;
    const int sub = lane & 15;
    const int grp16 = (tid >> 6) * 4 + (lane >> 4);   // 0..15
    const ushort4* __restrict__ x4 = reinterpret_cast<const ushort4*>(xin);

    // stage W2 k-half 0 now so the loads fly under the gather
    for (int i = tid; i < 512; i += 256)
        reinterpret_cast<float4*>(Wl)[i] = reinterpret_cast<const float4*>(W2)[i];

    // ---- gather phase: 4 edges per group, software-pipelined unroll-4 ----
    #pragma unroll
    for (int rr = 0; rr < 4; ++rr) {
        const int rl = grp16 * 4 + rr;          // local row 0..63
        const int e = row0 + rl;
        int2 sc = make_int2(0, 0);
        if (e < E) sc = seg[e];
        const int s = sc.x, c = sc.y;
        float4 acc = make_float4(0.f, 0.f, 0.f, 0.f);
        int i = 0;
        if (c >= 4) {
            int2 q0 = tri[s + 0];
            int2 q1 = tri[s + 1];
            int2 q2 = tri[s + 2];
            int2 q3 = tri[s + 3];
            for (; i + 7 < c; i += 4) {
                int2 n0 = tri[s + i + 4];       // prefetch next batch's indices
                int2 n1 = tri[s + i + 5];
                int2 n2 = tri[s + i + 6];
                int2 n3 = tri[s + i + 7];
                ushort4 ua0 = x4[(size_t)q0.x * 16 + sub];
                ushort4 ub0 = x4[(size_t)q0.y * 16 + sub];
                ushort4 ua1 = x4[(size_t)q1.x * 16 + sub];
                ushort4 ub1 = x4[(size_t)q1.y * 16 + sub];
                ushort4 ua2 = x4[(size_t)q2.x * 16 + sub];
                ushort4 ub2 = x4[(size_t)q2.y * 16 + sub];
                ushort4 ua3 = x4[(size_t)q3.x * 16 + sub];
                ushort4 ub3 = x4[(size_t)q3.y * 16 + sub];
                acc.x += bf2f(ua0.x) * bf2f(ub0.x); acc.y += bf2f(ua0.y) * bf2f(ub0.y);
                acc.z += bf2f(ua0.z) * bf2f(ub0.z); acc.w += bf2f(ua0.w) * bf2f(ub0.w);
                acc.x += bf2f(ua1.x) * bf2f(ub1.x); acc.y += bf2f(ua1.y) * bf2f(ub1.y);
                acc.z += bf2f(ua1.z) * bf2f(ub1.z); acc.w += bf2f(ua1.w) * bf2f(ub1.w);
                acc.x += bf2f(ua2.x) * bf2f(ub2.x); acc.y += bf2f(ua2.y) * bf2f(ub2.y);
                acc.z += bf2f(ua2.z) * bf2f(ub2.z); acc.w += bf2f(ua2.w) * bf2f(ub2.w);
                acc.x += bf2f(ua3.x) * bf2f(ub3.x); acc.y += bf2f(ua3.y) * bf2f(ub3.y);
                acc.z += bf2f(ua3.z) * bf2f(ub3.z); acc.w += bf2f(ua3.w) * bf2f(ub3.w);
                q0 = n0; q1 = n1; q2 = n2; q3 = n3;
            }
            {
                ushort4 ua0 = x4[(size_t)q0.x * 16 + sub];
                ushort4 ub0 = x4[(size_t)q0.y * 16 + sub];
                ushort4 ua1 = x4[(size_t)q1.x * 16 + sub];
                ushort4 ub1 = x4[(size_t)q1.y * 16 + sub];
                ushort4 ua2 = x4[(size_t)q2.x * 16 + sub];
                ushort4 ub2 = x4[(size_t)q2.y * 16 + sub];
                ushort4 ua3 = x4[(size_t)q3.x * 16 + sub];
                ushort4 ub3 = x4[(size_t)q3.y * 16 + sub];
                acc.x += bf2f(ua0.x) * bf2f(ub0.x); acc.y += bf2f(ua0.y) * bf2f(ub0.y);
                acc.z += bf2f(ua0.z) * bf2f(ub0.z); acc.w += bf2f(ua0.w) * bf2f(ub0.w);
                acc.x += bf2f(ua1.x) * bf2f(ub1.x); acc.y += bf2f(ua1.y) * bf2f(ub1.y);
                acc.z += bf2f(ua1.z) * bf2f(ub1.z); acc.w += bf2f(ua1.w) * bf2f(ub1.w);
                acc.x += bf2f(ua2.x) * bf2f(ub2.x); acc.y += bf2f(ua2.y) * bf2f(ub2.y);
                acc.z += bf2f(ua2.z) * bf2f(ub2.z); acc.w += bf2f(ua2.w) * bf2f(ub2.w);
                acc.x += bf2f(ua3.x) * bf2f(ub3.x); acc.y += bf2f(ua3.y) * bf2f(ub3.y);
                acc.z += bf2f(ua3.z) * bf2f(ub3.z); acc.w += bf2f(ua3.w) * bf2f(ub3.w);
            }
            i += 4;
        }
        for (; i < c; ++i) {
            int2 pp = tri[s + i];
            ushort4 ua = x4[(size_t)pp.x * 16 + sub];
            ushort4 ub = x4[(size_t)pp.y * 16 + sub];
            acc.x += bf2f(ua.x) * bf2f(ub.x);
            acc.y += bf2f(ua.y) * bf2f(ub.y);
            acc.z += bf2f(ua.z) * bf2f(ub.z);
            acc.w += bf2f(ua.w) * bf2f(ub.w);
        }
        fT[(sub * 4 + 0) * FPAD + rl] = acc.x;
        fT[(sub * 4 + 1) * FPAD + rl] = acc.y;
        fT[(sub * 4 + 2) * FPAD + rl] = acc.z;
        fT[(sub * 4 + 3) * FPAD + rl] = acc.w;
    }
    __syncthreads();

    const int j0 = (tid & 15) * 4;
    const int r0 = (tid >> 4) * 4;

    // ---- phase A: xa = relu(agg @ W2 + b2), W2 staged in two k-halves ----
    float accA[4][4];
    #pragma unroll
    for (int i = 0; i < 4; ++i)
        #pragma unroll
        for (int j = 0; j < 4; ++j) accA[i][j] = 0.f;

    #pragma unroll 8
    for (int k = 0; k < 32; ++k) {
        float4 f = *reinterpret_cast<const float4*>(&fT[k * FPAD + r0]);
        float4 w = *reinterpret_cast<const float4*>(&Wl[k * 64 + j0]);
        float fa[4] = {f.x, f.y, f.z, f.w};
        float wa[4] = {w.x, w.y, w.z, w.w};
        #pragma unroll
        for (int i = 0; i < 4; ++i)
            #pragma unroll
            for (int j = 0; j < 4; ++j) accA[i][j] += fa[i] * wa[j];
    }
    __syncthreads();
    for (int i = tid; i < 512; i += 256)
        reinterpret_cast<float4*>(Wl)[i] = reinterpret_cast<const float4*>(W2)[512 + i];
    __syncthreads();
    #pragma unroll 8
    for (int k = 0; k < 32; ++k) {
        float4 f = *reinterpret_cast<const float4*>(&fT[(32 + k) * FPAD + r0]);
        float4 w = *reinterpret_cast<const float4*>(&Wl[k * 64 + j0]);
        float fa[4] = {f.x, f.y, f.z, f.w};
        float wa[4] = {w.x, w.y, w.z, w.w};
        #pragma unroll
        for (int i = 0; i < 4; ++i)
            #pragma unroll
            for (int j = 0; j < 4; ++j) accA[i][j] += fa[i] * wa[j];
    }

    {
        float4 bv = *reinterpret_cast<const float4*>(&b2[j0]);
        float ba[4] = {bv.x, bv.y, bv.z, bv.w};
        #pragma unroll
        for (int i = 0; i < 4; ++i)
            #pragma unroll
            for (int j = 0; j < 4; ++j) accA[i][j] = relu_f(accA[i][j] + ba[j]);
    }

    __syncthreads();                    // all fT/Wl readers done

    // ---- phase B: fT = xa^T ; Wl = mW1 k-rows 0..31, cols 0..63 ----
    #pragma unroll
    for (int i = 0; i < 4; ++i)
        #pragma unroll
        for (int j = 0; j < 4; ++j)
            fT[(j0 + j) * FPAD + (r0 + i)] = accA[i][j];
    for (int i = tid; i < 512; i += 256) {
        int k = i >> 4, q = i & 15;
        *reinterpret_cast<float4*>(&Wl[k * 64 + q * 4]) =
            *reinterpret_cast<const float4*>(&mW1[(size_t)k * 128 + q * 4]);
    }
    __syncthreads();

    int etc_[4];
    #pragma unroll
    for (int i = 0; i < 4; ++i) {
        int row = row0 + r0 + i;
        etc_[i] = (row < E) ? et[row] : 0;
    }

    float p[4] = {0.f, 0.f, 0.f, 0.f};

    // ---- phase C, j-half 0 ----
    {
        float acc2[4][4];
        #pragma unroll
        for (int i = 0; i < 4; ++i)
            #pragma unroll
            for (int j = 0; j < 4; ++j) acc2[i][j] = 0.f;
        #pragma unroll 8
        for (int k = 0; k < 32; ++k) {
            float4 f = *reinterpret_cast<const float4*>(&fT[k * FPAD + r0]);
            float4 w = *reinterpret_cast<const float4*>(&Wl[k * 64 + j0]);
            float fa[4] = {f.x, f.y, f.z, f.w};
            float wa[4] = {w.x, w.y, w.z, w.w};
            #pragma unroll
            for (int i = 0; i < 4; ++i)
                #pragma unroll
                for (int j = 0; j < 4; ++j) acc2[i][j] += fa[i] * wa[j];
        }
        __syncthreads();
        for (int i = tid; i < 512; i += 256) {
            int k = i >> 4, q = i & 15;
            *reinterpret_cast<float4*>(&Wl[k * 64 + q * 4]) =
                *reinterpret_cast<const float4*>(&mW1[(size_t)(32 + k) * 128 + q * 4]);
        }
        __syncthreads();
        #pragma unroll 8
        for (int k = 0; k < 32; ++k) {
            float4 f = *reinterpret_cast<const float4*>(&fT[(32 + k) * FPAD + r0]);
            float4 w = *reinterpret_cast<const float4*>(&Wl[k * 64 + j0]);
            float fa[4] = {f.x, f.y, f.z, f.w};
            float wa[4] = {w.x, w.y, w.z, w.w};
            #pragma unroll
            for (int i = 0; i < 4; ++i)
                #pragma unroll
                for (int j = 0; j < 4; ++j) acc2[i][j] += fa[i] * wa[j];
        }
        float4 w2v = *reinterpret_cast<const float4*>(&mW2[j0]);
        #pragma unroll
        for (int i = 0; i < 4; ++i) {
            float4 qv = *reinterpret_cast<const float4*>(&Q[(size_t)etc_[i] * 128 + j0]);
            p[i] += relu_f(acc2[i][0] + qv.x) * w2v.x;
            p[i] += relu_f(acc2[i][1] + qv.y) * w2v.y;
            p[i] += relu_f(acc2[i][2] + qv.z) * w2v.z;
            p[i] += relu_f(acc2[i][3] + qv.w) * w2v.w;
        }
    }
    __syncthreads();                    // Wl readers done
    for (int i = tid; i < 512; i += 256) {
        int k = i >> 4, q = i & 15;
        *reinterpret_cast<float4*>(&Wl[k * 64 + q * 4]) =
            *reinterpret_cast<const float4*>(&mW1[(size_t)k * 128 + 64 + q * 4]);
    }
    __syncthreads();
    // ---- phase C, j-half 1 ----
    {
        float acc2[4][4];
        #pragma unroll
        for (int i = 0; i < 4; ++i)
            #pragma unroll
            for (int j = 0; j < 4; ++j) acc2[i][j] = 0.f;
        #pragma unroll 8
        for (int k = 0; k < 32; ++k) {
            float4 f = *reinterpret_cast<const float4*>(&fT[k * FPAD + r0]);
            float4 w = *reinterpret_cast<const float4*>(&Wl[k * 64 + j0]);
            float fa[4] = {f.x, f.y, f.z, f.w};
            float wa[4] = {w.x, w.y, w.z, w.w};
            #pragma unroll
            for (int i = 0; i < 4; ++i)
                #pragma unroll
                for (int j = 0; j < 4; ++j) acc2[i][j] += fa[i] * wa[j];
        }
        __syncthreads();
        for (int i = tid; i < 512; i += 256) {
            int k = i >> 4, q = i & 15;
            *reinterpret_cast<float4*>(&Wl[k * 64 + q * 4]) =
                *reinterpret_cast<const float4*>(&mW1[(size_t)(32 + k) * 128 + 64 + q * 4]);
        }
        __syncthreads();
        #pragma unroll 8
        for (int k = 0; k < 32; ++k) {
            float4 f = *reinterpret_cast<const float4*>(&fT[(32 + k) * FPAD + r0]);
            float4 w = *reinterpret_cast<const float4*>(&Wl[k * 64 + j0]);
            float fa[4] = {f.x, f.y, f.z, f.w};
            float wa[4] = {w.x, w.y, w.z, w.w};
            #pragma unroll
            for (int i = 0; i < 4; ++i)
                #pragma unroll
                for (int j = 0; j < 4; ++j) acc2[i][j] += fa[i] * wa[j];
        }
        float4 w2v = *reinterpret_cast<const float4*>(&mW2[64 + j0]);
        #pragma unroll
        for (int i = 0; i < 4; ++i) {
            float4 qv = *reinterpret_cast<const float4*>(&Q[(size_t)etc_[i] * 128 + 64 + j0]);
            p[i] += relu_f(acc2[i][0] + qv.x) * w2v.x;
            p[i] += relu_f(acc2[i][1] + qv.y) * w2v.y;
            p[i] += relu_f(acc2[i][2] + qv.z) * w2v.z;
            p[i] += relu_f(acc2[i][3] + qv.w) * w2v.w;
        }
    }

    const float bias2 = mb2[0];
    #pragma unroll
    for (int i = 0; i < 4; ++i) {
        float s = p[i];
        s += __shfl_xor(s, 1, 64);
        s += __shfl_xor(s, 2, 64);
        s += __shfl_xor(s, 4, 64);
        s += __shfl_xor(s, 8, 64);
        if ((tid & 15) == 0) {
            int row = row0 + r0 + i;
            if (row < E) out[row] = s + bias2;
        }
    }
}

extern "C" void kernel_launch(void* const* d_in, const int* in_sizes, int n_in,
                              void* d_out, int out_size, void* d_ws, size_t ws_size,
                              hipStream_t stream) {
    const int*   edge_type = (const int*)d_in[0];
    const int*   ab        = (const int*)d_in[1];
    const int*   bc        = (const int*)d_in[2];
    const int*   ac        = (const int*)d_in[3];
    const float* fe        = (const float*)d_in[4];
    const float* W1        = (const float*)d_in[5];
    const float* b1        = (const float*)d_in[6];
    const float* W2        = (const float*)d_in[7];
    const float* b2        = (const float*)d_in[8];
    const float* mW1       = (const float*)d_in[9];
    const float* mb1       = (const float*)d_in[10];
    const float* mW2       = (const float*)d_in[11];
    const float* mb2       = (const float*)d_in[12];

    const int E = in_sizes[0];
    const int T = in_sizes[1];
    const int nrel = in_sizes[4] / D;       // 102
    const int npair = nrel * nrel;
    float* out = (float*)d_out;

    // workspace layout
    char* p = (char*)d_ws;
    unsigned short* xb = (unsigned short*)p;  p += (size_t)E * D * sizeof(unsigned short);
    float* P    = (float*)p;   p += (size_t)npair * D * sizeof(float);
    float* Q    = (float*)p;   p += (size_t)nrel * 128 * sizeof(float);
    int* cnt    = (int*)p;     p += (size_t)E * sizeof(int);
    int* lexcl  = (int*)p;     p += (size_t)E * sizeof(int);
    int* cursor = (int*)p;     p += (size_t)E * sizeof(int);
    int* bsums  = (int*)p;     p += 256 * sizeof(int);
    int2* seg   = (int2*)p;    p += (size_t)E * sizeof(int2);
    int2* tri   = (int2*)p;    p += (size_t)T * sizeof(int2);
    int* pid    = (int*)p;     p += (size_t)T * sizeof(int);

    const int nblkA = (E + 1023) / 1024;
    const int nZ = (E + 1023) / 1024;
    const int nP = (npair + 63) / 64;
    const int nQb = (nrel + 1) / 2;

    k_prep<<<nZ + nP + nQb, 256, 0, stream>>>(cnt, E, fe, W1, P, nrel, mW1, mb1, Q, nZ, nP);
    k_hist<<<(T + 255) / 256, 256, 0, stream>>>(ac, cnt, T);
    k_scanA<<<nblkA, 256, 0, stream>>>(cnt, lexcl, bsums, E);
    k_scanC<<<(E + 255) / 256, 256, 0, stream>>>(lexcl, bsums, cnt, seg, cursor, E, nblkA);
    k_permute<<<(T + 255) / 256, 256, 0, stream>>>(ab, bc, ac, edge_type, cursor, tri, pid, T, nrel);

    const int MSG_BLOCKS = 2048;
    const int nquad = MSG_BLOCKS * 256 / 64;   // one wave per 4 edges
    k_msg1b<<<MSG_BLOCKS, 256, 0, stream>>>(seg, pid, P, b1, xb, E, nquad);
    k_msgmlp<<<(E + 63) / 64, 256, 0, stream>>>(seg, tri, xb, edge_type, Q,
                                                W2, b2, mW1, mW2, mb2, out, E);
}

// Round 25
// 158.119 us; speedup vs baseline: 1.0085x; 1.0085x over previous
//
#include <hip/hip_runtime.h>

#define D 64
#define FPAD 65

__device__ __forceinline__ float relu_f(float v) { return v > 0.f ? v : 0.f; }

// ---------------- fused prep: zero cnt | pair table | Q table ----------------
__global__ __launch_bounds__(256) void k_prep(int* __restrict__ cnt, int En,
        const float* __restrict__ fe, const float* __restrict__ W1,
        float* __restrict__ P, int nrel,
        const float* __restrict__ mW1, const float* __restrict__ mb1,
        float* __restrict__ Q, int nZ, int nP) {
    __shared__ float Wl[64 * 64];
    __shared__ float fT[64 * FPAD];
    const int tid = threadIdx.x;
    int b = blockIdx.x;

    if (b < nZ) {                       // ---- zero ----
        int i = (b * 256 + tid) * 4;
        if (i + 3 < En) {
            *reinterpret_cast<int4*>(cnt + i) = make_int4(0, 0, 0, 0);
        } else {
            for (int k = i; k < En; ++k) cnt[k] = 0;
        }
        return;
    }
    b -= nZ;
    if (b < nP) {                       // ---- pair table ----
        const int npair = nrel * nrel;
        const int p0 = b * 64;

        for (int i = tid; i < 1024; i += 256)
            reinterpret_cast<float4*>(Wl)[i] = reinterpret_cast<const float4*>(W1)[i];

        for (int i = tid; i < 1024; i += 256) {
            int r = i >> 4, q = i & 15;
            int p = p0 + r;
            float4 v = make_float4(0.f, 0.f, 0.f, 0.f);
            if (p < npair) {
                int pa = p / nrel, pb = p - pa * nrel;
                float4 va = reinterpret_cast<const float4*>(fe + (size_t)pa * D)[q];
                float4 vb = reinterpret_cast<const float4*>(fe + (size_t)pb * D)[q];
                v = make_float4(va.x * vb.x, va.y * vb.y, va.z * vb.z, va.w * vb.w);
            }
            fT[(q * 4 + 0) * FPAD + r] = v.x;
            fT[(q * 4 + 1) * FPAD + r] = v.y;
            fT[(q * 4 + 2) * FPAD + r] = v.z;
            fT[(q * 4 + 3) * FPAD + r] = v.w;
        }
        __syncthreads();

        const int j0 = (tid & 15) * 4;
        const int r0 = (tid >> 4) * 4;
        float acc[4][4];
        #pragma unroll
        for (int i = 0; i < 4; ++i)
            #pragma unroll
            for (int j = 0; j < 4; ++j) acc[i][j] = 0.f;

        #pragma unroll 8
        for (int k = 0; k < 64; ++k) {
            float4 f = *reinterpret_cast<const float4*>(&fT[k * FPAD + r0]);
            float4 w = *reinterpret_cast<const float4*>(&Wl[k * 64 + j0]);
            float fa[4] = {f.x, f.y, f.z, f.w};
            float wa[4] = {w.x, w.y, w.z, w.w};
            #pragma unroll
            for (int i = 0; i < 4; ++i)
                #pragma unroll
                for (int j = 0; j < 4; ++j) acc[i][j] += fa[i] * wa[j];
        }

        #pragma unroll
        for (int i = 0; i < 4; ++i) {
            int p = p0 + r0 + i;
            if (p < npair) {
                float4 o = make_float4(acc[i][0], acc[i][1], acc[i][2], acc[i][3]);
                *reinterpret_cast<float4*>(P + (size_t)p * D + j0) = o;
            }
        }
        return;
    }
    b -= nP;                            // ---- Q table (2 t's per block) ----
    int t = b * 2 + (tid >> 7);
    int j = tid & 127;
    float* fl = &fT[(tid >> 7) * 64];
    if (t < nrel && j < 64) fl[j] = fe[(size_t)t * D + j];
    __syncthreads();
    if (t < nrel) {
        float s = mb1[j];
        #pragma unroll 16
        for (int k = 0; k < 64; ++k)
            s += fl[k] * mW1[(size_t)(64 + k) * 128 + j];
        Q[(size_t)t * 128 + j] = s;
    }
}

// ---------------- CSR build ----------------

__global__ void k_hist(const int* __restrict__ ac, int* __restrict__ cnt, int T) {
    int t = blockIdx.x * blockDim.x + threadIdx.x;
    if (t < T) atomicAdd(&cnt[ac[t]], 1);
}

__global__ __launch_bounds__(256) void k_scanA(const int* __restrict__ cnt,
        int* __restrict__ localExcl, int* __restrict__ blockSums, int E) {
    __shared__ int ls[256];
    const int tid = threadIdx.x;
    int base = blockIdx.x * 1024 + tid * 4;
    int a0 = 0, a1 = 0, a2 = 0, a3 = 0;
    if (base + 3 < E) {
        int4 v = *reinterpret_cast<const int4*>(cnt + base);
        a0 = v.x; a1 = v.y; a2 = v.z; a3 = v.w;
    } else {
        if (base + 0 < E) a0 = cnt[base + 0];
        if (base + 1 < E) a1 = cnt[base + 1];
        if (base + 2 < E) a2 = cnt[base + 2];
        if (base + 3 < E) a3 = cnt[base + 3];
    }
    int tsum = a0 + a1 + a2 + a3;
    ls[tid] = tsum;
    __syncthreads();
    for (int off = 1; off < 256; off <<= 1) {
        int v = (tid >= off) ? ls[tid - off] : 0;
        __syncthreads();
        ls[tid] += v;
        __syncthreads();
    }
    int excl = ls[tid] - tsum;
    if (tid == 255) blockSums[blockIdx.x] = ls[255];
    if (base + 3 < E) {
        int4 o = make_int4(excl, excl + a0, excl + a0 + a1, excl + a0 + a1 + a2);
        *reinterpret_cast<int4*>(localExcl + base) = o;
    } else {
        int run = excl;
        if (base + 0 < E) { localExcl[base + 0] = run; run += a0; }
        if (base + 1 < E) { localExcl[base + 1] = run; run += a1; }
        if (base + 2 < E) { localExcl[base + 2] = run; run += a2; }
        if (base + 3 < E) { localExcl[base + 3] = run; }
    }
}

// scanC with integrated scan of blockSums (nblk <= 256)
__global__ __launch_bounds__(256) void k_scanC(const int* __restrict__ localExcl,
        const int* __restrict__ blockSums, const int* __restrict__ cnt,
        int2* __restrict__ seg, int* __restrict__ cursor, int E, int nblk) {
    __shared__ int ls[256];
    const int tid = threadIdx.x;
    int v = (tid < nblk) ? blockSums[tid] : 0;
    ls[tid] = v;
    __syncthreads();
    for (int off = 1; off < 256; off <<= 1) {
        int w = (tid >= off) ? ls[tid - off] : 0;
        __syncthreads();
        ls[tid] += w;
        __syncthreads();
    }
    int excl = ls[tid] - v;     // exclusive prefix of blockSums
    __syncthreads();
    ls[tid] = excl;
    __syncthreads();
    int i = blockIdx.x * blockDim.x + tid;
    if (i < E) {
        int s = localExcl[i] + ls[i >> 10];
        seg[i] = make_int2(s, cnt[i]);
        cursor[i] = s;
    }
}

// tri[pos] = (ab, bc); pid[pos] = et[ab]*nrel + et[bc]
__global__ void k_permute(const int* __restrict__ ab, const int* __restrict__ bc,
                          const int* __restrict__ ac, const int* __restrict__ et,
                          int* __restrict__ cursor, int2* __restrict__ tri,
                          int* __restrict__ pid, int T, int nrel) {
    int t = blockIdx.x * blockDim.x + threadIdx.x;
    if (t >= T) return;
    int a = ab[t], b = bc[t];
    int pos = atomicAdd(&cursor[ac[t]], 1);
    tri[pos] = make_int2(a, b);
    pid[pos] = et[a] * nrel + et[b];
}

// ---------------- layer-1: xb[e] = relu(sum_t P[pid_t] + b1) ----------------
__global__ __launch_bounds__(256) void k_msg1b(const int2* __restrict__ seg,
        const int* __restrict__ pid, const float* __restrict__ P,
        const float* __restrict__ b1, float* __restrict__ xb, int E, int nquad) {
    const int tid = threadIdx.x;
    const int lane = tid & 63;
    const int sub = lane & 15;
    const int grp = lane >> 4;
    const float4* __restrict__ P4 = reinterpret_cast<const float4*>(P);
    const float4 bb = reinterpret_cast<const float4*>(b1)[sub];

    for (int quad = (blockIdx.x * blockDim.x + tid) >> 6; quad * 4 < E; quad += nquad) {
        const int e = quad * 4 + grp;
        int2 sc = make_int2(0, 0);
        if (e < E) sc = seg[e];
        const int s = sc.x, c = sc.y;
        float4 acc = make_float4(0.f, 0.f, 0.f, 0.f);
        int i = 0;
        for (; i + 3 < c; i += 4) {
            int q0 = pid[s + i + 0];
            int q1 = pid[s + i + 1];
            int q2 = pid[s + i + 2];
            int q3 = pid[s + i + 3];
            float4 v0 = P4[(size_t)q0 * 16 + sub];
            float4 v1 = P4[(size_t)q1 * 16 + sub];
            float4 v2 = P4[(size_t)q2 * 16 + sub];
            float4 v3 = P4[(size_t)q3 * 16 + sub];
            acc.x += v0.x + v1.x + v2.x + v3.x;
            acc.y += v0.y + v1.y + v2.y + v3.y;
            acc.z += v0.z + v1.z + v2.z + v3.z;
            acc.w += v0.w + v1.w + v2.w + v3.w;
        }
        for (; i < c; ++i) {
            float4 v = P4[(size_t)pid[s + i] * 16 + sub];
            acc.x += v.x; acc.y += v.y; acc.z += v.z; acc.w += v.w;
        }
        if (e < E) {
            float4 o;
            o.x = relu_f(acc.x + bb.x);
            o.y = relu_f(acc.y + bb.y);
            o.z = relu_f(acc.z + bb.z);
            o.w = relu_f(acc.w + bb.w);
            reinterpret_cast<float4*>(xb + (size_t)e * D)[sub] = o;
        }
    }
}

// ---------------- fused layer-2: gather + linear + final MLP ----------------
// 64 edges / 256 thr. Wl 8 KB (k-half staging of W2/mW1), fT 16.6 KB ->
// LDS 24.8 KB. Gather: proven software-pipelined unroll-4.
__global__ __launch_bounds__(256) void k_msgmlp(const int2* __restrict__ seg,
        const int2* __restrict__ tri, const float* __restrict__ xin,
        const int* __restrict__ et, const float* __restrict__ Q,
        const float* __restrict__ W2, const float* __restrict__ b2,
        const float* __restrict__ mW1, const float* __restrict__ mW2,
        const float* __restrict__ mb2, float* __restrict__ out, int E) {
    __shared__ float Wl[32 * 64];       // 8 KB: one k-half of a 64-col panel
    __shared__ float fT[64 * FPAD];     // 16.6 KB (agg^T, then xa^T)
    const int tid = threadIdx.x;
    const int row0 = blockIdx.x * 64;
    const int lane = tid & 63;
    const int sub = lane & 15;
    const int grp16 = (tid >> 6) * 4 + (lane >> 4);   // 0..15
    const float4* __restrict__ x4 = reinterpret_cast<const float4*>(xin);

    // stage W2 k-half 0 now so the loads fly under the gather
    for (int i = tid; i < 512; i += 256)
        reinterpret_cast<float4*>(Wl)[i] = reinterpret_cast<const float4*>(W2)[i];

    // ---- gather phase: 4 edges per group, software-pipelined unroll-4 ----
    #pragma unroll
    for (int rr = 0; rr < 4; ++rr) {
        const int rl = grp16 * 4 + rr;          // local row 0..63
        const int e = row0 + rl;
        int2 sc = make_int2(0, 0);
        if (e < E) sc = seg[e];
        const int s = sc.x, c = sc.y;
        float4 acc = make_float4(0.f, 0.f, 0.f, 0.f);
        int i = 0;
        if (c >= 4) {
            int2 q0 = tri[s + 0];
            int2 q1 = tri[s + 1];
            int2 q2 = tri[s + 2];
            int2 q3 = tri[s + 3];
            for (; i + 7 < c; i += 4) {
                int2 n0 = tri[s + i + 4];       // prefetch next batch's indices
                int2 n1 = tri[s + i + 5];
                int2 n2 = tri[s + i + 6];
                int2 n3 = tri[s + i + 7];
                float4 va0 = x4[(size_t)q0.x * 16 + sub];
                float4 vb0 = x4[(size_t)q0.y * 16 + sub];
                float4 va1 = x4[(size_t)q1.x * 16 + sub];
                float4 vb1 = x4[(size_t)q1.y * 16 + sub];
                float4 va2 = x4[(size_t)q2.x * 16 + sub];
                float4 vb2 = x4[(size_t)q2.y * 16 + sub];
                float4 va3 = x4[(size_t)q3.x * 16 + sub];
                float4 vb3 = x4[(size_t)q3.y * 16 + sub];
                acc.x += va0.x * vb0.x; acc.y += va0.y * vb0.y;
                acc.z += va0.z * vb0.z; acc.w += va0.w * vb0.w;
                acc.x += va1.x * vb1.x; acc.y += va1.y * vb1.y;
                acc.z += va1.z * vb1.z; acc.w += va1.w * vb1.w;
                acc.x += va2.x * vb2.x; acc.y += va2.y * vb2.y;
                acc.z += va2.z * vb2.z; acc.w += va2.w * vb2.w;
                acc.x += va3.x * vb3.x; acc.y += va3.y * vb3.y;
                acc.z += va3.z * vb3.z; acc.w += va3.w * vb3.w;
                q0 = n0; q1 = n1; q2 = n2; q3 = n3;
            }
            {
                float4 va0 = x4[(size_t)q0.x * 16 + sub];
                float4 vb0 = x4[(size_t)q0.y * 16 + sub];
                float4 va1 = x4[(size_t)q1.x * 16 + sub];
                float4 vb1 = x4[(size_t)q1.y * 16 + sub];
                float4 va2 = x4[(size_t)q2.x * 16 + sub];
                float4 vb2 = x4[(size_t)q2.y * 16 + sub];
                float4 va3 = x4[(size_t)q3.x * 16 + sub];
                float4 vb3 = x4[(size_t)q3.y * 16 + sub];
                acc.x += va0.x * vb0.x; acc.y += va0.y * vb0.y;
                acc.z += va0.z * vb0.z; acc.w += va0.w * vb0.w;
                acc.x += va1.x * vb1.x; acc.y += va1.y * vb1.y;
                acc.z += va1.z * vb1.z; acc.w += va1.w * vb1.w;
                acc.x += va2.x * vb2.x; acc.y += va2.y * vb2.y;
                acc.z += va2.z * vb2.z; acc.w += va2.w * vb2.w;
                acc.x += va3.x * vb3.x; acc.y += va3.y * vb3.y;
                acc.z += va3.z * vb3.z; acc.w += va3.w * vb3.w;
            }
            i += 4;
        }
        for (; i < c; ++i) {
            int2 pp = tri[s + i];
            float4 va = x4[(size_t)pp.x * 16 + sub];
            float4 vb = x4[(size_t)pp.y * 16 + sub];
            acc.x += va.x * vb.x;
            acc.y += va.y * vb.y;
            acc.z += va.z * vb.z;
            acc.w += va.w * vb.w;
        }
        fT[(sub * 4 + 0) * FPAD + rl] = acc.x;
        fT[(sub * 4 + 1) * FPAD + rl] = acc.y;
        fT[(sub * 4 + 2) * FPAD + rl] = acc.z;
        fT[(sub * 4 + 3) * FPAD + rl] = acc.w;
    }
    __syncthreads();

    const int j0 = (tid & 15) * 4;
    const int r0 = (tid >> 4) * 4;

    // ---- phase A: xa = relu(agg @ W2 + b2), W2 staged in two k-halves ----
    float accA[4][4];
    #pragma unroll
    for (int i = 0; i < 4; ++i)
        #pragma unroll
        for (int j = 0; j < 4; ++j) accA[i][j] = 0.f;

    #pragma unroll 8
    for (int k = 0; k < 32; ++k) {
        float4 f = *reinterpret_cast<const float4*>(&fT[k * FPAD + r0]);
        float4 w = *reinterpret_cast<const float4*>(&Wl[k * 64 + j0]);
        float fa[4] = {f.x, f.y, f.z, f.w};
        float wa[4] = {w.x, w.y, w.z, w.w};
        #pragma unroll
        for (int i = 0; i < 4; ++i)
            #pragma unroll
            for (int j = 0; j < 4; ++j) accA[i][j] += fa[i] * wa[j];
    }
    __syncthreads();
    for (int i = tid; i < 512; i += 256)
        reinterpret_cast<float4*>(Wl)[i] = reinterpret_cast<const float4*>(W2)[512 + i];
    __syncthreads();
    #pragma unroll 8
    for (int k = 0; k < 32; ++k) {
        float4 f = *reinterpret_cast<const float4*>(&fT[(32 + k) * FPAD + r0]);
        float4 w = *reinterpret_cast<const float4*>(&Wl[k * 64 + j0]);
        float fa[4] = {f.x, f.y, f.z, f.w};
        float wa[4] = {w.x, w.y, w.z, w.w};
        #pragma unroll
        for (int i = 0; i < 4; ++i)
            #pragma unroll
            for (int j = 0; j < 4; ++j) accA[i][j] += fa[i] * wa[j];
    }

    {
        float4 bv = *reinterpret_cast<const float4*>(&b2[j0]);
        float ba[4] = {bv.x, bv.y, bv.z, bv.w};
        #pragma unroll
        for (int i = 0; i < 4; ++i)
            #pragma unroll
            for (int j = 0; j < 4; ++j) accA[i][j] = relu_f(accA[i][j] + ba[j]);
    }

    __syncthreads();                    // all fT/Wl readers done

    // ---- phase B: fT = xa^T ; Wl = mW1 k-rows 0..31, cols 0..63 ----
    #pragma unroll
    for (int i = 0; i < 4; ++i)
        #pragma unroll
        for (int j = 0; j < 4; ++j)
            fT[(j0 + j) * FPAD + (r0 + i)] = accA[i][j];
    for (int i = tid; i < 512; i += 256) {
        int k = i >> 4, q = i & 15;
        *reinterpret_cast<float4*>(&Wl[k * 64 + q * 4]) =
            *reinterpret_cast<const float4*>(&mW1[(size_t)k * 128 + q * 4]);
    }
    __syncthreads();

    int etc_[4];
    #pragma unroll
    for (int i = 0; i < 4; ++i) {
        int row = row0 + r0 + i;
        etc_[i] = (row < E) ? et[row] : 0;
    }

    float p[4] = {0.f, 0.f, 0.f, 0.f};

    // ---- phase C, j-half 0 ----
    {
        float acc2[4][4];
        #pragma unroll
        for (int i = 0; i < 4; ++i)
            #pragma unroll
            for (int j = 0; j < 4; ++j) acc2[i][j] = 0.f;
        #pragma unroll 8
        for (int k = 0; k < 32; ++k) {
            float4 f = *reinterpret_cast<const float4*>(&fT[k * FPAD + r0]);
            float4 w = *reinterpret_cast<const float4*>(&Wl[k * 64 + j0]);
            float fa[4] = {f.x, f.y, f.z, f.w};
            float wa[4] = {w.x, w.y, w.z, w.w};
            #pragma unroll
            for (int i = 0; i < 4; ++i)
                #pragma unroll
                for (int j = 0; j < 4; ++j) acc2[i][j] += fa[i] * wa[j];
        }
        __syncthreads();
        for (int i = tid; i < 512; i += 256) {
            int k = i >> 4, q = i & 15;
            *reinterpret_cast<float4*>(&Wl[k * 64 + q * 4]) =
                *reinterpret_cast<const float4*>(&mW1[(size_t)(32 + k) * 128 + q * 4]);
        }
        __syncthreads();
        #pragma unroll 8
        for (int k = 0; k < 32; ++k) {
            float4 f = *reinterpret_cast<const float4*>(&fT[(32 + k) * FPAD + r0]);
            float4 w = *reinterpret_cast<const float4*>(&Wl[k * 64 + j0]);
            float fa[4] = {f.x, f.y, f.z, f.w};
            float wa[4] = {w.x, w.y, w.z, w.w};
            #pragma unroll
            for (int i = 0; i < 4; ++i)
                #pragma unroll
                for (int j = 0; j < 4; ++j) acc2[i][j] += fa[i] * wa[j];
        }
        float4 w2v = *reinterpret_cast<const float4*>(&mW2[j0]);
        #pragma unroll
        for (int i = 0; i < 4; ++i) {
            float4 qv = *reinterpret_cast<const float4*>(&Q[(size_t)etc_[i] * 128 + j0]);
            p[i] += relu_f(acc2[i][0] + qv.x) * w2v.x;
            p[i] += relu_f(acc2[i][1] + qv.y) * w2v.y;
            p[i] += relu_f(acc2[i][2] + qv.z) * w2v.z;
            p[i] += relu_f(acc2[i][3] + qv.w) * w2v.w;
        }
    }
    __syncthreads();                    // Wl readers done
    for (int i = tid; i < 512; i += 256) {
        int k = i >> 4, q = i & 15;
        *reinterpret_cast<float4*>(&Wl[k * 64 + q * 4]) =
            *reinterpret_cast<const float4*>(&mW1[(size_t)k * 128 + 64 + q * 4]);
    }
    __syncthreads();
    // ---- phase C, j-half 1 ----
    {
        float acc2[4][4];
        #pragma unroll
        for (int i = 0; i < 4; ++i)
            #pragma unroll
            for (int j = 0; j < 4; ++j) acc2[i][j] = 0.f;
        #pragma unroll 8
        for (int k = 0; k < 32; ++k) {
            float4 f = *reinterpret_cast<const float4*>(&fT[k * FPAD + r0]);
            float4 w = *reinterpret_cast<const float4*>(&Wl[k * 64 + j0]);
            float fa[4] = {f.x, f.y, f.z, f.w};
            float wa[4] = {w.x, w.y, w.z, w.w};
            #pragma unroll
            for (int i = 0; i < 4; ++i)
                #pragma unroll
                for (int j = 0; j < 4; ++j) acc2[i][j] += fa[i] * wa[j];
        }
        __syncthreads();
        for (int i = tid; i < 512; i += 256) {
            int k = i >> 4, q = i & 15;
            *reinterpret_cast<float4*>(&Wl[k * 64 + q * 4]) =
                *reinterpret_cast<const float4*>(&mW1[(size_t)(32 + k) * 128 + 64 + q * 4]);
        }
        __syncthreads();
        #pragma unroll 8
        for (int k = 0; k < 32; ++k) {
            float4 f = *reinterpret_cast<const float4*>(&fT[(32 + k) * FPAD + r0]);
            float4 w = *reinterpret_cast<const float4*>(&Wl[k * 64 + j0]);
            float fa[4] = {f.x, f.y, f.z, f.w};
            float wa[4] = {w.x, w.y, w.z, w.w};
            #pragma unroll
            for (int i = 0; i < 4; ++i)
                #pragma unroll
                for (int j = 0; j < 4; ++j) acc2[i][j] += fa[i] * wa[j];
        }
        float4 w2v = *reinterpret_cast<const float4*>(&mW2[64 + j0]);
        #pragma unroll
        for (int i = 0; i < 4; ++i) {
            float4 qv = *reinterpret_cast<const float4*>(&Q[(size_t)etc_[i] * 128 + 64 + j0]);
            p[i] += relu_f(acc2[i][0] + qv.x) * w2v.x;
            p[i] += relu_f(acc2[i][1] + qv.y) * w2v.y;
            p[i] += relu_f(acc2[i][2] + qv.z) * w2v.z;
            p[i] += relu_f(acc2[i][3] + qv.w) * w2v.w;
        }
    }

    const float bias2 = mb2[0];
    #pragma unroll
    for (int i = 0; i < 4; ++i) {
        float s = p[i];
        s += __shfl_xor(s, 1, 64);
        s += __shfl_xor(s, 2, 64);
        s += __shfl_xor(s, 4, 64);
        s += __shfl_xor(s, 8, 64);
        if ((tid & 15) == 0) {
            int row = row0 + r0 + i;
            if (row < E) out[row] = s + bias2;
        }
    }
}

extern "C" void kernel_launch(void* const* d_in, const int* in_sizes, int n_in,
                              void* d_out, int out_size, void* d_ws, size_t ws_size,
                              hipStream_t stream) {
    const int*   edge_type = (const int*)d_in[0];
    const int*   ab        = (const int*)d_in[1];
    const int*   bc        = (const int*)d_in[2];
    const int*   ac        = (const int*)d_in[3];
    const float* fe        = (const float*)d_in[4];
    const float* W1        = (const float*)d_in[5];
    const float* b1        = (const float*)d_in[6];
    const float* W2        = (const float*)d_in[7];
    const float* b2        = (const float*)d_in[8];
    const float* mW1       = (const float*)d_in[9];
    const float* mb1       = (const float*)d_in[10];
    const float* mW2       = (const float*)d_in[11];
    const float* mb2       = (const float*)d_in[12];

    const int E = in_sizes[0];
    const int T = in_sizes[1];
    const int nrel = in_sizes[4] / D;       // 102
    const int npair = nrel * nrel;
    float* out = (float*)d_out;

    // workspace layout
    char* p = (char*)d_ws;
    float* xb   = (float*)p;   p += (size_t)E * D * sizeof(float);
    float* P    = (float*)p;   p += (size_t)npair * D * sizeof(float);
    float* Q    = (float*)p;   p += (size_t)nrel * 128 * sizeof(float);
    int* cnt    = (int*)p;     p += (size_t)E * sizeof(int);
    int* lexcl  = (int*)p;     p += (size_t)E * sizeof(int);
    int* cursor = (int*)p;     p += (size_t)E * sizeof(int);
    int* bsums  = (int*)p;     p += 256 * sizeof(int);
    int2* seg   = (int2*)p;    p += (size_t)E * sizeof(int2);
    int2* tri   = (int2*)p;    p += (size_t)T * sizeof(int2);
    int* pid    = (int*)p;     p += (size_t)T * sizeof(int);

    const int nblkA = (E + 1023) / 1024;
    const int nZ = (E + 1023) / 1024;
    const int nP = (npair + 63) / 64;
    const int nQb = (nrel + 1) / 2;

    k_prep<<<nZ + nP + nQb, 256, 0, stream>>>(cnt, E, fe, W1, P, nrel, mW1, mb1, Q, nZ, nP);
    k_hist<<<(T + 255) / 256, 256, 0, stream>>>(ac, cnt, T);
    k_scanA<<<nblkA, 256, 0, stream>>>(cnt, lexcl, bsums, E);
    k_scanC<<<(E + 255) / 256, 256, 0, stream>>>(lexcl, bsums, cnt, seg, cursor, E, nblkA);
    k_permute<<<(T + 255) / 256, 256, 0, stream>>>(ab, bc, ac, edge_type, cursor, tri, pid, T, nrel);

    const int MSG_BLOCKS = 2048;
    const int nquad = MSG_BLOCKS * 256 / 64;   // one wave per 4 edges
    k_msg1b<<<MSG_BLOCKS, 256, 0, stream>>>(seg, pid, P, b1, xb, E, nquad);
    k_msgmlp<<<(E + 63) / 64, 256, 0, stream>>>(seg, tri, xb, edge_type, Q,
                                                W2, b2, mW1, mW2, mb2, out, E);
}